// Round 8
// baseline (3239.060 us; speedup 1.0000x reference)
//
#include <hip/hip_runtime.h>
#include <stdint.h>

typedef uint16_t u16;
typedef uint32_t u32;
typedef __bf16 bf16_t;
typedef float f32x4 __attribute__((ext_vector_type(4)));

static __device__ __forceinline__ float bf2f(u16 v){
  union { u32 u; float f; } x; x.u = ((u32)v) << 16; return x.f;
}
static __device__ __forceinline__ u16 f2bf(float f){
  union { bf16_t b; u16 u; } cv; cv.b = (bf16_t)f; return cv.u;
}

// ---------------- K0: raw relative-bias table [dh+31][h][dw+31] (63*512 f32) --------------
__global__ __launch_bounds__(256) void k_bias_setup(
    const float* __restrict__ dist_bias, const float* __restrict__ dir_bias,
    float* __restrict__ ebtab)
{
  int tid = blockIdx.x*256 + threadIdx.x;
  if (tid >= 63*63) return;
  int dhi = tid / 63, dwi = tid % 63;
  int dh = dhi - 31, dw = dwi - 31;
  int r2 = dh*dh + dw*dw;
  int dist = (int)sqrtf((float)r2);   // exact floor for r2 <= 1922
  if (dist > 59) dist = 59;
  int dir;
  if (dh==0 && dw==0)      dir = 0;
  else if (dh==0)          dir = (dw>0) ? 8  : 0;
  else if (dw==0)          dir = (dh>0) ? 12 : 4;
  else if (dh==dw)         dir = (dh>0) ? 10 : 2;
  else if (dh==-dw)        dir = (dh>0) ? 14 : 6;
  else {
    float ang = atan2f((float)dh, (float)dw) + 3.14159265358979323846f;
    int k = (int)floorf(ang * 2.5464790894703254f);  // *16/(2pi)
    dir = k & 15;
  }
  for (int h=0; h<8; h++){
    ebtab[dhi*512 + h*64 + dwi] = dist_bias[dist*8+h] + dir_bias[dir*8+h];
  }
}

// ---------------- K1: C[8192][256] = X @ W^T + b  (f32 in, f32 VALU, bf16 out) ------------
__global__ __launch_bounds__(256) void k_gemm(
    const float* __restrict__ X, const float* __restrict__ W,
    const float* __restrict__ Bv, u16* __restrict__ Out)
{
  __shared__ float Xs[32*256];
  __shared__ float Wsh[16*256];
  const int t = threadIdx.x;
  const int m0 = blockIdx.x * 32;

  {
    int r = t>>3, c0 = (t&7)*32;
    const float* gp = X + (size_t)(m0+r)*256 + c0;
    float* lp = &Xs[r*256 + c0];
    #pragma unroll
    for (int i=0;i<8;i++) *(f32x4*)(lp + 4*i) = *(const f32x4*)(gp + 4*i);
  }
  __syncthreads();

  const int m  = t>>3;
  const int c2 = (t&7)*2;

  for (int cg=0; cg<16; cg++){
    {
      int r = t>>4, c0 = (t&15)*16;
      const float* gp = W + (size_t)(cg*16+r)*256 + c0;
      float* lp = &Wsh[r*256 + c0];
      #pragma unroll
      for (int i=0;i<4;i++) *(f32x4*)(lp + 4*i) = *(const f32x4*)(gp + 4*i);
    }
    __syncthreads();
    float acc0 = 0.0f, acc1 = 0.0f;
    for (int k=0;k<256;k++){
      float xv = Xs[m*256 + k];
      acc0 += xv * Wsh[c2*256 + k];
      acc1 += xv * Wsh[(c2+1)*256 + k];
    }
    int col = cg*16 + c2;
    Out[(size_t)(m0+m)*256 + col]     = f2bf(acc0 + Bv[col]);
    Out[(size_t)(m0+m)*256 + col + 1] = f2bf(acc1 + Bv[col+1]);
    __syncthreads();
  }
}

// ---------------- K2: ctx only. q computed on the fly. One block per (b,q). ---------------
__global__ __launch_bounds__(256) void k_attn_ctx(
    const float* __restrict__ x, const float* __restrict__ wq,
    const float* __restrict__ bq,
    const u16* __restrict__ K, const u16* __restrict__ V,
    const float* __restrict__ ebtab, u16* __restrict__ ctx)
{
  __shared__ float xrow[256];
  __shared__ float qrow[256];
  __shared__ float sc[8192];     // biased exp numerators [h][j]
  __shared__ float wred[4][8];
  __shared__ float den[8];

  const int t  = threadIdx.x;
  const int b  = blockIdx.y;
  const int q  = blockIdx.x;
  const int qh = q >> 5, qw = q & 31;
  const int wv = t >> 6;

  xrow[t] = x[(size_t)(b*1024 + q)*256 + t];
  __syncthreads();
  {
    const float* wr_ = wq + (size_t)t*256;
    float a = 0.0f;
    for (int k=0;k<256;k++) a += xrow[k] * wr_[k];
    qrow[t] = (a + bq[t]) * 0.17677669529663687f;   // 1/sqrt(32)
  }
  __syncthreads();

  float pb[8];
  #pragma unroll
  for (int h=0;h<8;h++) pb[h]=0.0f;

  for (int i=0;i<4;i++){
    int j = t + 256*i;
    int jh = j>>5, jw = j&31;
    const u16* Krow = K + (size_t)(b*1024 + j)*256;
    const float* eb = ebtab + (jh - qh + 31)*512 + (jw - qw + 31);
    #pragma unroll
    for (int h=0;h<8;h++){
      float a = 0.0f;
      for (int d=0;d<32;d++) a += qrow[h*32+d] * bf2f(Krow[h*32+d]);
      float e = __expf(a + eb[h*64]);
      sc[h*1024 + j] = e;
      pb[h] += e;
    }
  }
  #pragma unroll
  for (int h=0;h<8;h++){
    float vb = pb[h];
    #pragma unroll
    for (int m=1;m<64;m<<=1) vb += __shfl_xor(vb, m, 64);
    if ((t&63)==0) wred[wv][h] = vb;
  }
  __syncthreads();
  if (t < 8) den[t] = wred[0][t] + wred[1][t] + wred[2][t] + wred[3][t];
  __syncthreads();

  {
    int h = t >> 5;
    const u16* Vb = V + (size_t)(b*1024)*256 + t;
    const float* ps = &sc[h*1024];
    float acc = 0.0f;
    for (int j=0;j<1024;j++) acc += ps[j] * bf2f(Vb[(size_t)j*256]);
    ctx[(size_t)(b*1024 + q)*256 + t] = f2bf(acc / den[h]);
  }
}

// ---------------- K3: out = ctx@Wo^T + bo ; y = LN(out + x). f32 output. ------------------
__global__ __launch_bounds__(256) void k_outln_cons(
    const u16* __restrict__ CX, const float* __restrict__ Wo,
    const float* __restrict__ bo, const float* __restrict__ xs,
    const float* __restrict__ lgm, const float* __restrict__ lbt,
    float* __restrict__ Out)
{
  __shared__ float crow[256];
  __shared__ float wr[4][2];
  __shared__ float mv[2];
  const int t = threadIdx.x;
  const int s = blockIdx.x;
  const int wv = t >> 6;

  crow[t] = bf2f(CX[(size_t)s*256 + t]);
  __syncthreads();

  const float* worow = Wo + (size_t)t*256;
  float acc = 0.0f;
  for (int k=0;k<256;k++) acc += crow[k] * worow[k];
  float y = acc + bo[t] + xs[(size_t)s*256 + t];

  float s1 = y, s2 = y*y;
  #pragma unroll
  for (int m=1;m<64;m<<=1){ s1 += __shfl_xor(s1, m, 64); s2 += __shfl_xor(s2, m, 64); }
  if ((t&63)==0){ wr[wv][0] = s1; wr[wv][1] = s2; }
  __syncthreads();
  if (t < 2) mv[t] = wr[0][t] + wr[1][t] + wr[2][t] + wr[3][t];
  __syncthreads();
  float mu  = mv[0] * 0.00390625f;
  float var = mv[1] * 0.00390625f - mu*mu;
  float rs  = rsqrtf(var + 1e-5f);
  Out[(size_t)s*256 + t] = (y - mu)*rs*lgm[t] + lbt[t];
}

// ---------------- K4: attn_w (no bias), f32 out, runs LAST over dead V/CX scratch ---------
__global__ __launch_bounds__(256) void k_attnw(
    const float* __restrict__ x, const float* __restrict__ wq,
    const float* __restrict__ bq, const u16* __restrict__ K,
    float* __restrict__ awout)
{
  __shared__ float xrow[256];
  __shared__ float qrow[256];
  __shared__ float sc[8192];
  __shared__ float wred[4][8];
  __shared__ float den[8];

  const int t  = threadIdx.x;
  const int b  = blockIdx.y;
  const int q  = blockIdx.x;
  const int wv = t >> 6;

  xrow[t] = x[(size_t)(b*1024 + q)*256 + t];
  __syncthreads();
  {
    const float* wr_ = wq + (size_t)t*256;
    float a = 0.0f;
    for (int k=0;k<256;k++) a += xrow[k] * wr_[k];
    qrow[t] = (a + bq[t]) * 0.17677669529663687f;
  }
  __syncthreads();

  float pp[8];
  #pragma unroll
  for (int h=0;h<8;h++) pp[h]=0.0f;

  for (int i=0;i<4;i++){
    int j = t + 256*i;
    const u16* Krow = K + (size_t)(b*1024 + j)*256;
    #pragma unroll
    for (int h=0;h<8;h++){
      float a = 0.0f;
      for (int d=0;d<32;d++) a += qrow[h*32+d] * bf2f(Krow[h*32+d]);
      float e = __expf(a);
      sc[h*1024 + j] = e;
      pp[h] += e;
    }
  }
  #pragma unroll
  for (int h=0;h<8;h++){
    float vp = pp[h];
    #pragma unroll
    for (int m=1;m<64;m<<=1) vp += __shfl_xor(vp, m, 64);
    if ((t&63)==0) wred[wv][h] = vp;
  }
  __syncthreads();
  if (t < 8) den[t] = wred[0][t] + wred[1][t] + wred[2][t] + wred[3][t];
  __syncthreads();

  float rp[8];
  #pragma unroll
  for (int h=0;h<8;h++) rp[h] = 1.0f/den[h];

  for (int i=0;i<4;i++){
    int j = t + 256*i;
    float aw = 0.0f;
    #pragma unroll
    for (int h=0;h<8;h++) aw += sc[h*1024 + j] * rp[h];
    awout[(size_t)(b*1024 + q)*1024 + j] = aw * 0.125f;
  }
}

// -----------------------------------------------------------------------------------------
extern "C" void kernel_launch(void* const* d_in, const int* in_sizes, int n_in,
                              void* d_out, int out_size, void* d_ws, size_t ws_size,
                              hipStream_t stream)
{
  const float* x   = (const float*)d_in[0];
  const float* wq  = (const float*)d_in[1];
  const float* bq  = (const float*)d_in[2];
  const float* wk  = (const float*)d_in[3];
  const float* bk  = (const float*)d_in[4];
  const float* wv_ = (const float*)d_in[5];
  const float* bv  = (const float*)d_in[6];
  const float* wo  = (const float*)d_in[7];
  const float* bo  = (const float*)d_in[8];
  const float* lng = (const float*)d_in[9];
  const float* lnb = (const float*)d_in[10];
  const float* dib = (const float*)d_in[11];
  const float* drb = (const float*)d_in[12];

  // ws: ebtab 129 KB + K 4 MB bf16 = 4.33 MB (proven in-bounds).
  // d_out is FLOAT: y = f32[0..2M) ; attn_w = f32[2M..10.5M) (33.5 MB).
  //   bf16 scratch inside attn_w region (dead before k_attnw runs last):
  //   V = u16[4MB) at aw bytes [0,4M), CX = u16[4MB) at aw bytes [4M,8M).
  char* ws = (char*)d_ws;
  float* ebtab = (float*)ws;
  u16*   K     = (u16*)(ws + 131072);
  float* y     = (float*)d_out;
  float* aw    = y + 2097152;
  u16*   V     = (u16*)aw;
  u16*   CX    = (u16*)((char*)aw + 4194304);

  k_bias_setup<<<16, 256, 0, stream>>>(dib, drb, ebtab);
  k_gemm<<<256, 256, 0, stream>>>(x, wk, bk, K);
  k_gemm<<<256, 256, 0, stream>>>(x, wv_, bv, V);
  k_attn_ctx<<<dim3(1024, 8), 256, 0, stream>>>(x, wq, bq, K, V, ebtab, CX);
  k_outln_cons<<<8192, 256, 0, stream>>>(CX, wo, bo, x, lng, lnb, y);
  k_attnw<<<dim3(1024, 8), 256, 0, stream>>>(x, wq, bq, K, aw);
}

// Round 9
// 319.405 us; speedup vs baseline: 10.1409x; 10.1409x over previous
//
#include <hip/hip_runtime.h>
#include <stdint.h>

typedef uint16_t u16;
typedef uint32_t u32;
typedef __bf16 bf16_t;
typedef __bf16 bf16x8 __attribute__((ext_vector_type(8)));
typedef __bf16 bf16x4 __attribute__((ext_vector_type(4)));
typedef float  f32x4  __attribute__((ext_vector_type(4)));

#define MFMA16(a,b,c) __builtin_amdgcn_mfma_f32_16x16x32_bf16(a,b,c,0,0,0)

static __device__ __forceinline__ u16 f2bf(float f){
  union { bf16_t b; u16 u; } cv; cv.b = (bf16_t)f; return cv.u;
}
static __device__ __forceinline__ float bf2f(u16 v){
  union { u32 u; float f; } x; x.u = ((u32)v) << 16; return x.f;
}
static __device__ __forceinline__ u32 pack2(float a, float b){
  return (u32)f2bf(a) | ((u32)f2bf(b) << 16);
}

// ---------------- K0: exp(bias) table [dh+31][h][dw+31] (63*512 f32) ----------------------
__global__ __launch_bounds__(256) void k_bias_setup(
    const float* __restrict__ dist_bias, const float* __restrict__ dir_bias,
    float* __restrict__ ebtab)
{
  int tid = blockIdx.x*256 + threadIdx.x;
  if (tid >= 63*63) return;
  int dhi = tid / 63, dwi = tid % 63;
  int dh = dhi - 31, dw = dwi - 31;
  int r2 = dh*dh + dw*dw;
  int dist = (int)sqrtf((float)r2);
  if (dist > 59) dist = 59;
  int dir;
  if (dh==0 && dw==0)      dir = 0;
  else if (dh==0)          dir = (dw>0) ? 8  : 0;
  else if (dw==0)          dir = (dh>0) ? 12 : 4;
  else if (dh==dw)         dir = (dh>0) ? 10 : 2;
  else if (dh==-dw)        dir = (dh>0) ? 14 : 6;
  else {
    float ang = atan2f((float)dh, (float)dw) + 3.14159265358979323846f;
    int k = (int)floorf(ang * 2.5464790894703254f);
    dir = k & 15;
  }
  for (int h=0; h<8; h++){
    ebtab[dhi*512 + h*64 + dwi] = expf(dist_bias[dist*8+h] + dir_bias[dir*8+h]);
  }
}

// ---------------- K1: C[8192,256] = X @ W^T + b (f32 in, bf16 MFMA, bf16 out) -------------
// vt_mode=0: row-major out. vt_mode=1: transposed Vt[b][n][s].
__global__ __launch_bounds__(256) void k_proj(
    const float* __restrict__ X, const float* __restrict__ W,
    const float* __restrict__ Bv, u16* __restrict__ Out, float scale, int vt_mode)
{
  __shared__ bf16_t Xs[32*40];
  __shared__ bf16_t Wsh[256*40];
  __shared__ float  Cs[32*260];
  const int t = threadIdx.x;
  const int wv = t>>6, ln = t&15, qd = (t&63)>>4;
  const int wm = wv & 1, wn = wv >> 1;
  const int m0 = blockIdx.x * 32;

  f32x4 z4 = {0.0f,0.0f,0.0f,0.0f};
  f32x4 acc[8];
  #pragma unroll
  for (int i=0;i<8;i++) acc[i] = z4;

  for (int kt=0; kt<8; kt++){
    __syncthreads();
    { int m = t>>3, k0 = (t&7)*4;
      f32x4 v = *(const f32x4*)(X + (size_t)(m0+m)*256 + kt*32 + k0);
      uint2 pk; pk.x = pack2(v[0], v[1]); pk.y = pack2(v[2], v[3]);
      *(uint2*)&Xs[m*40 + k0] = pk;
    }
    #pragma unroll
    for (int j=0;j<8;j++){
      int n = (t>>3) + 32*j, k0 = (t&7)*4;
      f32x4 v = *(const f32x4*)(W + (size_t)n*256 + kt*32 + k0);
      uint2 pk; pk.x = pack2(v[0], v[1]); pk.y = pack2(v[2], v[3]);
      *(uint2*)&Wsh[n*40 + k0] = pk;
    }
    __syncthreads();
    bf16x8 a = *(const bf16x8*)&Xs[(wm*16+ln)*40 + qd*8];
    #pragma unroll
    for (int ni=0;ni<8;ni++){
      bf16x8 bb = *(const bf16x8*)&Wsh[(wn*128 + ni*16 + ln)*40 + qd*8];
      acc[ni] = MFMA16(a, bb, acc[ni]);
    }
  }
  __syncthreads();
  #pragma unroll
  for (int ni=0;ni<8;ni++){
    const int col = wn*128 + ni*16 + ln;
    const float bias = Bv[col];
    #pragma unroll
    for (int r=0;r<4;r++){
      Cs[(wm*16 + qd*4 + r)*260 + col] = (acc[ni][r] + bias) * scale;
    }
  }
  __syncthreads();
  if (!vt_mode){
    int row = t>>3, c0 = (t&7)*32;
    u16* op = Out + (size_t)(m0+row)*256 + c0;
    #pragma unroll
    for (int i=0;i<4;i++){
      f32x4 v0 = *(const f32x4*)&Cs[row*260 + c0 + i*8];
      f32x4 v1 = *(const f32x4*)&Cs[row*260 + c0 + i*8 + 4];
      union { u16 h[8]; uint4 v; } pk;
      #pragma unroll
      for (int e=0;e<4;e++){ pk.h[e] = f2bf(v0[e]); pk.h[4+e] = f2bf(v1[e]); }
      *(uint4*)(op + i*8) = pk.v;
    }
  } else {
    const int n = t;
    const int b = m0 >> 10, s0 = m0 & 1023;
    u16* op = Out + (size_t)(b*256 + n)*1024 + s0;
    #pragma unroll
    for (int i=0;i<4;i++){
      union { u16 h[8]; uint4 v; } pk;
      #pragma unroll
      for (int e=0;e<8;e++) pk.h[e] = f2bf(Cs[(i*8+e)*260 + n]);
      *(uint4*)(op + i*8) = pk.v;
    }
  }
}

// ---------------- K2: biased attention -> ctx (bf16). Block=(qt,b), wave owns 2 heads. ----
__global__ __launch_bounds__(256) void k_attn(
    const u16* __restrict__ Qg, const u16* __restrict__ Kg,
    const u16* __restrict__ Vtg, const float* __restrict__ ebtab,
    u16* __restrict__ ctx)
{
  __shared__ bf16_t Ks[32*264];
  __shared__ bf16_t Vt[256*44];
  __shared__ bf16_t Ps[4][16*40];
  __shared__ float  ebs[512];

  const int t  = threadIdx.x;
  const int wv = t >> 6;
  const int ln = t & 15;
  const int qd = (t & 63) >> 4;
  const int b  = blockIdx.y;
  const int qt = blockIdx.x;
  const int qh_img = qt >> 1;
  const int qw0 = (qt & 1) * 16;

  const u16* Qb  = Qg  + (size_t)(b*1024 + qt*16) * 256;
  const u16* Kb  = Kg  + (size_t)b * 1024 * 256;
  const u16* Vtb = Vtg + (size_t)b * 256 * 1024;

  f32x4 z4 = {0.0f,0.0f,0.0f,0.0f};

  bf16x8 aq[2];
  aq[0] = *(const bf16x8*)(Qb + ln*256 + wv*32 + qd*8);
  aq[1] = *(const bf16x8*)(Qb + ln*256 + (wv+4)*32 + qd*8);

  float ls[2][4];
  #pragma unroll
  for (int hi=0;hi<2;hi++)
    #pragma unroll
    for (int r=0;r<4;r++) ls[hi][r] = 0.0f;

  // ---- pass 1: biased exp sums ----
  for (int kt=0; kt<32; kt++){
    __syncthreads();
    { int r = t>>3, c0 = (t&7)*32;
      const u16* gp = Kb + (size_t)(kt*32 + r)*256 + c0;
      bf16_t* lp = &Ks[r*264 + c0];
      #pragma unroll
      for (int i=0;i<4;i++) *(uint4*)(lp + 8*i) = *(const uint4*)(gp + 8*i);
    }
    if (t < 128){
      *(f32x4*)&ebs[t*4] = *(const f32x4*)(ebtab + (kt - qh_img + 31)*512 + t*4);
    }
    __syncthreads();
    #pragma unroll
    for (int hi=0; hi<2; hi++){
      const int h = wv + hi*4;
      #pragma unroll
      for (int kh=0; kh<2; kh++){
        bf16x8 bk = *(const bf16x8*)&Ks[(kh*16+ln)*264 + h*32 + qd*8];
        f32x4 sc = MFMA16(aq[hi], bk, z4);
        const int kw = kh*16 + ln;
        #pragma unroll
        for (int r=0;r<4;r++){
          ls[hi][r] += exp2f(sc[r]) * ebs[h*64 + (kw - (qw0 + qd*4 + r)) + 31];
        }
      }
    }
  }
  #pragma unroll
  for (int hi=0;hi<2;hi++)
    #pragma unroll
    for (int r=0;r<4;r++){
      float v = ls[hi][r];
      #pragma unroll
      for (int m=1;m<16;m<<=1) v += __shfl_xor(v, m, 16);
      ls[hi][r] = 1.0f / v;
    }

  f32x4 oacc[2][2];
  oacc[0][0]=z4; oacc[0][1]=z4; oacc[1][0]=z4; oacc[1][1]=z4;

  // ---- pass 2: probs -> P@V ----
  for (int kt=0; kt<32; kt++){
    __syncthreads();
    { int r = t>>3, c0 = (t&7)*32;
      const u16* gp = Kb + (size_t)(kt*32 + r)*256 + c0;
      bf16_t* lp = &Ks[r*264 + c0];
      #pragma unroll
      for (int i=0;i<4;i++) *(uint4*)(lp + 8*i) = *(const uint4*)(gp + 8*i);
    }
    #pragma unroll
    for (int j=0;j<8;j++){
      int n = (t>>3) + 32*j, k0 = (t&7)*4;
      *(uint2*)&Vt[n*44 + k0] = *(const uint2*)(Vtb + (size_t)n*1024 + kt*32 + k0);
    }
    if (t < 128){
      *(f32x4*)&ebs[t*4] = *(const f32x4*)(ebtab + (kt - qh_img + 31)*512 + t*4);
    }
    __syncthreads();

    #pragma unroll
    for (int hi=0;hi<2;hi++){
      const int h = wv + hi*4;
      #pragma unroll
      for (int kh=0;kh<2;kh++){
        bf16x8 bk = *(const bf16x8*)&Ks[(kh*16+ln)*264 + h*32 + qd*8];
        f32x4 sc = MFMA16(aq[hi], bk, z4);
        const int kw = kh*16 + ln;
        #pragma unroll
        for (int r=0;r<4;r++){
          float eb = exp2f(sc[r]) * ebs[h*64 + (kw - (qw0 + qd*4 + r)) + 31];
          Ps[wv][(qd*4+r)*40 + kh*16 + ln] = (bf16_t)(eb * ls[hi][r]);
        }
      }
      asm volatile("s_waitcnt lgkmcnt(0)" ::: "memory");
      bf16x8 ap = *(const bf16x8*)&Ps[wv][ln*40 + qd*8];
      #pragma unroll
      for (int nh=0;nh<2;nh++){
        const int n = h*32 + nh*16 + ln;
        bf16x4 vlo = *(const bf16x4*)&Vt[n*44 + qd*8];
        bf16x4 vhi = *(const bf16x4*)&Vt[n*44 + qd*8 + 4];
        bf16x8 bv  = __builtin_shufflevector(vlo, vhi, 0,1,2,3,4,5,6,7);
        oacc[hi][nh] = MFMA16(ap, bv, oacc[hi][nh]);
      }
    }
  }

  #pragma unroll
  for (int hi=0;hi<2;hi++){
    const int h = wv + hi*4;
    #pragma unroll
    for (int nh=0;nh<2;nh++)
      #pragma unroll
      for (int r=0;r<4;r++)
        ctx[(size_t)(b*1024 + qt*16 + qd*4 + r)*256 + h*32 + nh*16 + ln]
            = f2bf(oacc[hi][nh][r]);
  }
}

// ---------------- K2b: plain softmax -> attn_w f32 (mean over heads) ----------------------
__global__ __launch_bounds__(256) void k_attnw(
    const u16* __restrict__ Qg, const u16* __restrict__ Kg,
    float* __restrict__ awout)
{
  __shared__ bf16_t Ks[32*264];
  __shared__ float  awp[4][16*33];

  const int t  = threadIdx.x;
  const int wv = t >> 6;
  const int ln = t & 15;
  const int qd = (t & 63) >> 4;
  const int b  = blockIdx.y;
  const int qt = blockIdx.x;

  const u16* Qb = Qg + (size_t)(b*1024 + qt*16) * 256;
  const u16* Kb = Kg + (size_t)b * 1024 * 256;

  f32x4 z4 = {0.0f,0.0f,0.0f,0.0f};

  bf16x8 aq[2];
  aq[0] = *(const bf16x8*)(Qb + ln*256 + wv*32 + qd*8);
  aq[1] = *(const bf16x8*)(Qb + ln*256 + (wv+4)*32 + qd*8);

  float ls[2][4];
  #pragma unroll
  for (int hi=0;hi<2;hi++)
    #pragma unroll
    for (int r=0;r<4;r++) ls[hi][r] = 0.0f;

  for (int kt=0; kt<32; kt++){
    __syncthreads();
    { int r = t>>3, c0 = (t&7)*32;
      const u16* gp = Kb + (size_t)(kt*32 + r)*256 + c0;
      bf16_t* lp = &Ks[r*264 + c0];
      #pragma unroll
      for (int i=0;i<4;i++) *(uint4*)(lp + 8*i) = *(const uint4*)(gp + 8*i);
    }
    __syncthreads();
    #pragma unroll
    for (int hi=0; hi<2; hi++){
      const int h = wv + hi*4;
      #pragma unroll
      for (int kh=0; kh<2; kh++){
        bf16x8 bk = *(const bf16x8*)&Ks[(kh*16+ln)*264 + h*32 + qd*8];
        f32x4 sc = MFMA16(aq[hi], bk, z4);
        #pragma unroll
        for (int r=0;r<4;r++) ls[hi][r] += exp2f(sc[r]);
      }
    }
  }
  #pragma unroll
  for (int hi=0;hi<2;hi++)
    #pragma unroll
    for (int r=0;r<4;r++){
      float v = ls[hi][r];
      #pragma unroll
      for (int m=1;m<16;m<<=1) v += __shfl_xor(v, m, 16);
      ls[hi][r] = 1.0f / v;
    }

  for (int kt=0; kt<32; kt++){
    __syncthreads();
    { int r = t>>3, c0 = (t&7)*32;
      const u16* gp = Kb + (size_t)(kt*32 + r)*256 + c0;
      bf16_t* lp = &Ks[r*264 + c0];
      #pragma unroll
      for (int i=0;i<4;i++) *(uint4*)(lp + 8*i) = *(const uint4*)(gp + 8*i);
    }
    __syncthreads();
    #pragma unroll
    for (int hi=0; hi<2; hi++){
      const int h = wv + hi*4;
      #pragma unroll
      for (int kh=0; kh<2; kh++){
        bf16x8 bk = *(const bf16x8*)&Ks[(kh*16+ln)*264 + h*32 + qd*8];
        f32x4 sc = MFMA16(aq[hi], bk, z4);
        #pragma unroll
        for (int r=0;r<4;r++){
          float p = exp2f(sc[r]) * ls[hi][r];
          if (hi==0) awp[wv][(qd*4+r)*33 + kh*16 + ln]  = p;
          else       awp[wv][(qd*4+r)*33 + kh*16 + ln] += p;
        }
      }
    }
    __syncthreads();
    { int row = t>>4, c = (t&15)*2;
      float s0=0.0f, s1=0.0f;
      #pragma unroll
      for (int w=0;w<4;w++){
        s0 += awp[w][row*33 + c];
        s1 += awp[w][row*33 + c + 1];
      }
      float2 o; o.x = s0*0.125f; o.y = s1*0.125f;
      *(float2*)(awout + (size_t)(b*1024 + qt*16 + row)*1024 + kt*32 + c) = o;
    }
  }
}

// ---------------- K3: out = ctx@Wo^T + bo ; y = LN(out + x). f32 out. ---------------------
__global__ __launch_bounds__(256) void k_outln(
    const u16* __restrict__ CX, const float* __restrict__ Wo,
    const float* __restrict__ bo, const float* __restrict__ xs,
    const float* __restrict__ lgm, const float* __restrict__ lbt,
    float* __restrict__ Out)
{
  __shared__ bf16_t Cts[32*40];
  __shared__ bf16_t Wsh[256*40];
  __shared__ float  Ys[32*260];
  __shared__ float  parts[2][32][2];
  const int t = threadIdx.x;
  const int wv = t>>6, ln = t&15, qd = (t&63)>>4;
  const int wm = wv & 1, wn = wv >> 1;
  const int m0 = blockIdx.x * 32;

  f32x4 z4 = {0.0f,0.0f,0.0f,0.0f};
  f32x4 acc[8];
  #pragma unroll
  for (int i=0;i<8;i++) acc[i] = z4;

  for (int kt=0; kt<8; kt++){
    __syncthreads();
    { int m = t>>3, k0 = (t&7)*4;
      *(uint2*)&Cts[m*40 + k0] = *(const uint2*)(CX + (size_t)(m0+m)*256 + kt*32 + k0);
    }
    #pragma unroll
    for (int j=0;j<8;j++){
      int n = (t>>3) + 32*j, k0 = (t&7)*4;
      f32x4 v = *(const f32x4*)(Wo + (size_t)n*256 + kt*32 + k0);
      uint2 pk; pk.x = pack2(v[0], v[1]); pk.y = pack2(v[2], v[3]);
      *(uint2*)&Wsh[n*40 + k0] = pk;
    }
    __syncthreads();
    bf16x8 a = *(const bf16x8*)&Cts[(wm*16+ln)*40 + qd*8];
    #pragma unroll
    for (int ni=0;ni<8;ni++){
      bf16x8 bb = *(const bf16x8*)&Wsh[(wn*128 + ni*16 + ln)*40 + qd*8];
      acc[ni] = MFMA16(a, bb, acc[ni]);
    }
  }

  float psum[4]={0,0,0,0}, psq[4]={0,0,0,0};
  #pragma unroll
  for (int ni=0;ni<8;ni++){
    const int col = wn*128 + ni*16 + ln;
    const float bias = bo[col];
    #pragma unroll
    for (int r=0;r<4;r++){
      const int row = wm*16 + qd*4 + r;
      float y = acc[ni][r] + bias + xs[(size_t)(m0+row)*256 + col];
      acc[ni][r] = y;
      psum[r] += y; psq[r] += y*y;
    }
  }
  #pragma unroll
  for (int r=0;r<4;r++){
    float a1 = psum[r], a2 = psq[r];
    #pragma unroll
    for (int m=1;m<16;m<<=1){ a1 += __shfl_xor(a1,m,16); a2 += __shfl_xor(a2,m,16); }
    if (ln == 0){
      parts[wn][wm*16 + qd*4 + r][0] = a1;
      parts[wn][wm*16 + qd*4 + r][1] = a2;
    }
  }
  __syncthreads();
  #pragma unroll
  for (int r=0;r<4;r++){
    const int row = wm*16 + qd*4 + r;
    float mu  = (parts[0][row][0] + parts[1][row][0]) * 0.00390625f;
    float var = (parts[0][row][1] + parts[1][row][1]) * 0.00390625f - mu*mu;
    float rs = rsqrtf(var + 1e-5f);
    #pragma unroll
    for (int ni=0;ni<8;ni++){
      const int col = wn*128 + ni*16 + ln;
      Ys[row*260 + col] = (acc[ni][r] - mu)*rs*lgm[col] + lbt[col];
    }
  }
  __syncthreads();
  { int row = t>>3, c0 = (t&7)*32;
    float* op = Out + (size_t)(m0+row)*256 + c0;
    #pragma unroll
    for (int i=0;i<8;i++)
      *(f32x4*)(op + 4*i) = *(const f32x4*)&Ys[row*260 + c0 + 4*i];
  }
}

// -----------------------------------------------------------------------------------------
extern "C" void kernel_launch(void* const* d_in, const int* in_sizes, int n_in,
                              void* d_out, int out_size, void* d_ws, size_t ws_size,
                              hipStream_t stream)
{
  const float* x   = (const float*)d_in[0];
  const float* wq  = (const float*)d_in[1];
  const float* bq  = (const float*)d_in[2];
  const float* wk  = (const float*)d_in[3];
  const float* bk  = (const float*)d_in[4];
  const float* wv_ = (const float*)d_in[5];
  const float* bv  = (const float*)d_in[6];
  const float* wo  = (const float*)d_in[7];
  const float* bo  = (const float*)d_in[8];
  const float* lng = (const float*)d_in[9];
  const float* lnb = (const float*)d_in[10];
  const float* dib = (const float*)d_in[11];
  const float* drb = (const float*)d_in[12];

  // ws: ebtab 129 KB + CX bf16 4 MB = 4.33 MB (proven safe footprint).
  // d_out f32: y [0, 8MB) ; attn_w [8MB, 41.5MB).
  //   Q bf16 at y bytes [0,4M), K bf16 at y bytes [4M,8M)  -> dead before k_outln writes y.
  //   Vt bf16 at aw bytes [0,4M)                           -> dead before k_attnw writes aw.
  char*  ws    = (char*)d_ws;
  float* ebtab = (float*)ws;
  u16*   CX    = (u16*)(ws + 131072);
  float* y     = (float*)d_out;
  float* aw    = y + 2097152;
  u16*   Q     = (u16*)y;
  u16*   K     = (u16*)((char*)y + 4194304);
  u16*   Vt    = (u16*)aw;

  const float qscale = 0.25503486f;   // log2(e)/sqrt(32) folded into Q

  k_bias_setup<<<16, 256, 0, stream>>>(dib, drb, ebtab);
  k_proj<<<256, 256, 0, stream>>>(x, wq, bq, Q,  qscale, 0);
  k_proj<<<256, 256, 0, stream>>>(x, wk, bk, K,  1.0f,   0);
  k_proj<<<256, 256, 0, stream>>>(x, wv_, bv, Vt, 1.0f,  1);
  k_attn<<<dim3(64, 8), 256, 0, stream>>>(Q, K, Vt, ebtab, CX);
  k_attnw<<<dim3(64, 8), 256, 0, stream>>>(Q, K, aw);      // overwrites Vt (dead)
  k_outln<<<256, 256, 0, stream>>>(CX, wo, bo, x, lng, lnb, y);  // overwrites Q,K (dead)
}

// Round 10
// 247.195 us; speedup vs baseline: 13.1032x; 1.2921x over previous
//
#include <hip/hip_runtime.h>
#include <stdint.h>

typedef uint16_t u16;
typedef uint32_t u32;
typedef __bf16 bf16_t;
typedef __bf16 bf16x8 __attribute__((ext_vector_type(8)));
typedef __bf16 bf16x4 __attribute__((ext_vector_type(4)));
typedef float  f32x4  __attribute__((ext_vector_type(4)));

#define MFMA16(a,b,c) __builtin_amdgcn_mfma_f32_16x16x32_bf16(a,b,c,0,0,0)

static __device__ __forceinline__ u16 f2bf(float f){
  union { bf16_t b; u16 u; } cv; cv.b = (bf16_t)f; return cv.u;
}
static __device__ __forceinline__ float bf2f(u16 v){
  union { u32 u; float f; } x; x.u = ((u32)v) << 16; return x.f;
}
static __device__ __forceinline__ u32 pack2(float a, float b){
  return (u32)f2bf(a) | ((u32)f2bf(b) << 16);
}

// ---------------- K0: exp(bias) table [dh+31][h][dw+31] (63*512 f32) ----------------------
__global__ __launch_bounds__(256) void k_bias_setup(
    const float* __restrict__ dist_bias, const float* __restrict__ dir_bias,
    float* __restrict__ ebtab)
{
  int tid = blockIdx.x*256 + threadIdx.x;
  if (tid >= 63*63) return;
  int dhi = tid / 63, dwi = tid % 63;
  int dh = dhi - 31, dw = dwi - 31;
  int r2 = dh*dh + dw*dw;
  int dist = (int)sqrtf((float)r2);
  if (dist > 59) dist = 59;
  int dir;
  if (dh==0 && dw==0)      dir = 0;
  else if (dh==0)          dir = (dw>0) ? 8  : 0;
  else if (dw==0)          dir = (dh>0) ? 12 : 4;
  else if (dh==dw)         dir = (dh>0) ? 10 : 2;
  else if (dh==-dw)        dir = (dh>0) ? 14 : 6;
  else {
    float ang = atan2f((float)dh, (float)dw) + 3.14159265358979323846f;
    int k = (int)floorf(ang * 2.5464790894703254f);
    dir = k & 15;
  }
  for (int h=0; h<8; h++){
    ebtab[dhi*512 + h*64 + dwi] = expf(dist_bias[dist*8+h] + dir_bias[dir*8+h]);
  }
}

// ---------------- K1: C[8192,256] = X @ W^T + b (f32 in, bf16 MFMA, bf16 out) -------------
// vt_mode=0: row-major out. vt_mode=1: transposed Vt[b][n][s].
__global__ __launch_bounds__(256) void k_proj(
    const float* __restrict__ X, const float* __restrict__ W,
    const float* __restrict__ Bv, u16* __restrict__ Out, float scale, int vt_mode)
{
  __shared__ bf16_t Xs[32*40];
  __shared__ bf16_t Wsh[256*40];
  __shared__ float  Cs[32*260];
  const int t = threadIdx.x;
  const int wv = t>>6, ln = t&15, qd = (t&63)>>4;
  const int wm = wv & 1, wn = wv >> 1;
  const int m0 = blockIdx.x * 32;

  f32x4 z4 = {0.0f,0.0f,0.0f,0.0f};
  f32x4 acc[8];
  #pragma unroll
  for (int i=0;i<8;i++) acc[i] = z4;

  for (int kt=0; kt<8; kt++){
    __syncthreads();
    { int m = t>>3, k0 = (t&7)*4;
      f32x4 v = *(const f32x4*)(X + (size_t)(m0+m)*256 + kt*32 + k0);
      uint2 pk; pk.x = pack2(v[0], v[1]); pk.y = pack2(v[2], v[3]);
      *(uint2*)&Xs[m*40 + k0] = pk;
    }
    #pragma unroll
    for (int j=0;j<8;j++){
      int n = (t>>3) + 32*j, k0 = (t&7)*4;
      f32x4 v = *(const f32x4*)(W + (size_t)n*256 + kt*32 + k0);
      uint2 pk; pk.x = pack2(v[0], v[1]); pk.y = pack2(v[2], v[3]);
      *(uint2*)&Wsh[n*40 + k0] = pk;
    }
    __syncthreads();
    bf16x8 a = *(const bf16x8*)&Xs[(wm*16+ln)*40 + qd*8];
    #pragma unroll
    for (int ni=0;ni<8;ni++){
      bf16x8 bb = *(const bf16x8*)&Wsh[(wn*128 + ni*16 + ln)*40 + qd*8];
      acc[ni] = MFMA16(a, bb, acc[ni]);
    }
  }
  __syncthreads();
  #pragma unroll
  for (int ni=0;ni<8;ni++){
    const int col = wn*128 + ni*16 + ln;
    const float bias = Bv[col];
    #pragma unroll
    for (int r=0;r<4;r++){
      Cs[(wm*16 + qd*4 + r)*260 + col] = (acc[ni][r] + bias) * scale;
    }
  }
  __syncthreads();
  if (!vt_mode){
    int row = t>>3, c0 = (t&7)*32;
    u16* op = Out + (size_t)(m0+row)*256 + c0;
    #pragma unroll
    for (int i=0;i<4;i++){
      f32x4 v0 = *(const f32x4*)&Cs[row*260 + c0 + i*8];
      f32x4 v1 = *(const f32x4*)&Cs[row*260 + c0 + i*8 + 4];
      union { u16 h[8]; uint4 v; } pk;
      #pragma unroll
      for (int e=0;e<4;e++){ pk.h[e] = f2bf(v0[e]); pk.h[4+e] = f2bf(v1[e]); }
      *(uint4*)(op + i*8) = pk.v;
    }
  } else {
    const int n = t;
    const int b = m0 >> 10, s0 = m0 & 1023;
    u16* op = Out + (size_t)(b*256 + n)*1024 + s0;
    #pragma unroll
    for (int i=0;i<4;i++){
      union { u16 h[8]; uint4 v; } pk;
      #pragma unroll
      for (int e=0;e<8;e++) pk.h[e] = f2bf(Cs[(i*8+e)*260 + n]);
      *(uint4*)(op + i*8) = pk.v;
    }
  }
}

// ---------------- K2: fused attention: ctx (biased softmax @ V) + attn_w (plain) ----------
// Pass 1: unnormalized-PV with both denominators. Pass 2: plain probs -> attn_w.
__global__ __launch_bounds__(256) void k_attn_fused(
    const u16* __restrict__ Qg, const u16* __restrict__ Kg,
    const u16* __restrict__ Vtg, const float* __restrict__ ebtab,
    u16* __restrict__ ctx, float* __restrict__ AW)
{
  __shared__ bf16_t Ks[32*264];            // 16896 B
  __shared__ __align__(16) char uvt[22528];// pass1: Vt bf16[256*44]; pass2: awp f32[4*528]
  __shared__ bf16_t Ps[4][16*40];          // 5120 B
  __shared__ float  ebs[512];              // 2048 B
  bf16_t* Vt  = (bf16_t*)uvt;
  float*  awp = (float*)uvt;

  const int t  = threadIdx.x;
  const int wv = t >> 6;
  const int ln = t & 15;
  const int qd = (t & 63) >> 4;
  const int b  = blockIdx.y;
  const int qt = blockIdx.x;
  const int qh_img = qt >> 1;
  const int qw0 = (qt & 1) * 16;

  const u16* Qb  = Qg  + (size_t)(b*1024 + qt*16) * 256;
  const u16* Kb  = Kg  + (size_t)b * 1024 * 256;
  const u16* Vtb = Vtg + (size_t)b * 256 * 1024;

  f32x4 z4 = {0.0f,0.0f,0.0f,0.0f};

  bf16x8 aq[2];
  aq[0] = *(const bf16x8*)(Qb + ln*256 + wv*32 + qd*8);
  aq[1] = *(const bf16x8*)(Qb + ln*256 + (wv+4)*32 + qd*8);

  float se[2][4], sb[2][4];
  #pragma unroll
  for (int hi=0;hi<2;hi++)
    #pragma unroll
    for (int r=0;r<4;r++){ se[hi][r]=0.0f; sb[hi][r]=0.0f; }

  f32x4 oacc[2][2];
  oacc[0][0]=z4; oacc[0][1]=z4; oacc[1][0]=z4; oacc[1][1]=z4;

  // ---- pass 1: exp once -> both denominators + unnormalized PV ----
  for (int kt=0; kt<32; kt++){
    __syncthreads();
    { int r = t>>3, c0 = (t&7)*32;
      const u16* gp = Kb + (size_t)(kt*32 + r)*256 + c0;
      bf16_t* lp = &Ks[r*264 + c0];
      #pragma unroll
      for (int i=0;i<4;i++) *(uint4*)(lp + 8*i) = *(const uint4*)(gp + 8*i);
    }
    #pragma unroll
    for (int j=0;j<8;j++){
      int n = (t>>3) + 32*j, k0 = (t&7)*4;
      *(uint2*)&Vt[n*44 + k0] = *(const uint2*)(Vtb + (size_t)n*1024 + kt*32 + k0);
    }
    if (t < 128){
      *(f32x4*)&ebs[t*4] = *(const f32x4*)(ebtab + (kt - qh_img + 31)*512 + t*4);
    }
    __syncthreads();

    #pragma unroll
    for (int hi=0;hi<2;hi++){
      const int h = wv + hi*4;
      #pragma unroll
      for (int kh=0;kh<2;kh++){
        bf16x8 bk = *(const bf16x8*)&Ks[(kh*16+ln)*264 + h*32 + qd*8];
        f32x4 sc = MFMA16(aq[hi], bk, z4);
        const int kw = kh*16 + ln;
        #pragma unroll
        for (int r=0;r<4;r++){
          float e  = exp2f(sc[r]);                 // Q pre-scaled by log2e/sqrt(dk)
          float eb = e * ebs[h*64 + (kw - (qw0 + qd*4 + r)) + 31];
          se[hi][r] += e;
          sb[hi][r] += eb;
          Ps[wv][(qd*4+r)*40 + kh*16 + ln] = (bf16_t)eb;   // unnormalized
        }
      }
      asm volatile("s_waitcnt lgkmcnt(0)" ::: "memory");
      bf16x8 ap = *(const bf16x8*)&Ps[wv][ln*40 + qd*8];
      #pragma unroll
      for (int nh=0;nh<2;nh++){
        const int n = h*32 + nh*16 + ln;
        bf16x4 vlo = *(const bf16x4*)&Vt[n*44 + qd*8];
        bf16x4 vhi = *(const bf16x4*)&Vt[n*44 + qd*8 + 4];
        bf16x8 bv  = __builtin_shufflevector(vlo, vhi, 0,1,2,3,4,5,6,7);
        oacc[hi][nh] = MFMA16(ap, bv, oacc[hi][nh]);
      }
    }
  }

  // reduce denominators across the 16 column-lanes (same qd group)
  float inv_se[2][4], inv_sb[2][4];
  #pragma unroll
  for (int hi=0;hi<2;hi++)
    #pragma unroll
    for (int r=0;r<4;r++){
      float a = se[hi][r], c = sb[hi][r];
      #pragma unroll
      for (int m=1;m<16;m<<=1){ a += __shfl_xor(a, m, 16); c += __shfl_xor(c, m, 16); }
      inv_se[hi][r] = 1.0f / a;
      inv_sb[hi][r] = 1.0f / c;
    }

  // ---- pass 2: plain probs -> attn_w (mean over heads) ----
  for (int kt=0; kt<32; kt++){
    __syncthreads();   // also guards uvt union (Vt reads done / awp reads of prev iter done)
    { int r = t>>3, c0 = (t&7)*32;
      const u16* gp = Kb + (size_t)(kt*32 + r)*256 + c0;
      bf16_t* lp = &Ks[r*264 + c0];
      #pragma unroll
      for (int i=0;i<4;i++) *(uint4*)(lp + 8*i) = *(const uint4*)(gp + 8*i);
    }
    __syncthreads();

    float paw[2][4];
    #pragma unroll
    for (int hi=0;hi<2;hi++){
      const int h = wv + hi*4;
      #pragma unroll
      for (int kh=0;kh<2;kh++){
        bf16x8 bk = *(const bf16x8*)&Ks[(kh*16+ln)*264 + h*32 + qd*8];
        f32x4 sc = MFMA16(aq[hi], bk, z4);
        #pragma unroll
        for (int r=0;r<4;r++){
          float p = exp2f(sc[r]) * inv_se[hi][r];
          if (hi==0) paw[kh][r]  = p;
          else       paw[kh][r] += p;
        }
      }
    }
    #pragma unroll
    for (int kh=0;kh<2;kh++)
      #pragma unroll
      for (int r=0;r<4;r++)
        awp[wv*528 + (qd*4+r)*33 + kh*16 + ln] = paw[kh][r];
    __syncthreads();
    { int row = t>>4, c = (t&15)*2;
      float s0=0.0f, s1=0.0f;
      #pragma unroll
      for (int w=0;w<4;w++){
        s0 += awp[w*528 + row*33 + c];
        s1 += awp[w*528 + row*33 + c + 1];
      }
      float2 o; o.x = s0*0.125f; o.y = s1*0.125f;
      *(float2*)(AW + (size_t)(b*1024 + qt*16 + row)*1024 + kt*32 + c) = o;
    }
  }

  // ---- ctx out (normalize by biased denominator) ----
  #pragma unroll
  for (int hi=0;hi<2;hi++){
    const int h = wv + hi*4;
    #pragma unroll
    for (int nh=0;nh<2;nh++)
      #pragma unroll
      for (int r=0;r<4;r++)
        ctx[(size_t)(b*1024 + qt*16 + qd*4 + r)*256 + h*32 + nh*16 + ln]
            = f2bf(oacc[hi][nh][r] * inv_sb[hi][r]);
  }
}

// ---------------- K3: out = ctx@Wo^T + bo ; y = LN(out + x). f32 out. ---------------------
__global__ __launch_bounds__(256) void k_outln(
    const u16* __restrict__ CX, const float* __restrict__ Wo,
    const float* __restrict__ bo, const float* __restrict__ xs,
    const float* __restrict__ lgm, const float* __restrict__ lbt,
    float* __restrict__ Out)
{
  __shared__ bf16_t Cts[32*40];
  __shared__ bf16_t Wsh[256*40];
  __shared__ float  Ys[32*260];
  __shared__ float  parts[2][32][2];
  const int t = threadIdx.x;
  const int wv = t>>6, ln = t&15, qd = (t&63)>>4;
  const int wm = wv & 1, wn = wv >> 1;
  const int m0 = blockIdx.x * 32;

  f32x4 z4 = {0.0f,0.0f,0.0f,0.0f};
  f32x4 acc[8];
  #pragma unroll
  for (int i=0;i<8;i++) acc[i] = z4;

  for (int kt=0; kt<8; kt++){
    __syncthreads();
    { int m = t>>3, k0 = (t&7)*4;
      *(uint2*)&Cts[m*40 + k0] = *(const uint2*)(CX + (size_t)(m0+m)*256 + kt*32 + k0);
    }
    #pragma unroll
    for (int j=0;j<8;j++){
      int n = (t>>3) + 32*j, k0 = (t&7)*4;
      f32x4 v = *(const f32x4*)(Wo + (size_t)n*256 + kt*32 + k0);
      uint2 pk; pk.x = pack2(v[0], v[1]); pk.y = pack2(v[2], v[3]);
      *(uint2*)&Wsh[n*40 + k0] = pk;
    }
    __syncthreads();
    bf16x8 a = *(const bf16x8*)&Cts[(wm*16+ln)*40 + qd*8];
    #pragma unroll
    for (int ni=0;ni<8;ni++){
      bf16x8 bb = *(const bf16x8*)&Wsh[(wn*128 + ni*16 + ln)*40 + qd*8];
      acc[ni] = MFMA16(a, bb, acc[ni]);
    }
  }

  float psum[4]={0,0,0,0}, psq[4]={0,0,0,0};
  #pragma unroll
  for (int ni=0;ni<8;ni++){
    const int col = wn*128 + ni*16 + ln;
    const float bias = bo[col];
    #pragma unroll
    for (int r=0;r<4;r++){
      const int row = wm*16 + qd*4 + r;
      float y = acc[ni][r] + bias + xs[(size_t)(m0+row)*256 + col];
      acc[ni][r] = y;
      psum[r] += y; psq[r] += y*y;
    }
  }
  #pragma unroll
  for (int r=0;r<4;r++){
    float a1 = psum[r], a2 = psq[r];
    #pragma unroll
    for (int m=1;m<16;m<<=1){ a1 += __shfl_xor(a1,m,16); a2 += __shfl_xor(a2,m,16); }
    if (ln == 0){
      parts[wn][wm*16 + qd*4 + r][0] = a1;
      parts[wn][wm*16 + qd*4 + r][1] = a2;
    }
  }
  __syncthreads();
  #pragma unroll
  for (int r=0;r<4;r++){
    const int row = wm*16 + qd*4 + r;
    float mu  = (parts[0][row][0] + parts[1][row][0]) * 0.00390625f;
    float var = (parts[0][row][1] + parts[1][row][1]) * 0.00390625f - mu*mu;
    float rs = rsqrtf(var + 1e-5f);
    #pragma unroll
    for (int ni=0;ni<8;ni++){
      const int col = wn*128 + ni*16 + ln;
      Ys[row*260 + col] = (acc[ni][r] - mu)*rs*lgm[col] + lbt[col];
    }
  }
  __syncthreads();
  { int row = t>>3, c0 = (t&7)*32;
    float* op = Out + (size_t)(m0+row)*256 + c0;
    #pragma unroll
    for (int i=0;i<8;i++)
      *(f32x4*)(op + 4*i) = *(const f32x4*)&Ys[row*260 + c0 + 4*i];
  }
}

// -----------------------------------------------------------------------------------------
extern "C" void kernel_launch(void* const* d_in, const int* in_sizes, int n_in,
                              void* d_out, int out_size, void* d_ws, size_t ws_size,
                              hipStream_t stream)
{
  const float* x   = (const float*)d_in[0];
  const float* wq  = (const float*)d_in[1];
  const float* bq  = (const float*)d_in[2];
  const float* wk  = (const float*)d_in[3];
  const float* bk  = (const float*)d_in[4];
  const float* wv_ = (const float*)d_in[5];
  const float* bv  = (const float*)d_in[6];
  const float* wo  = (const float*)d_in[7];
  const float* bo  = (const float*)d_in[8];
  const float* lng = (const float*)d_in[9];
  const float* lnb = (const float*)d_in[10];
  const float* dib = (const float*)d_in[11];
  const float* drb = (const float*)d_in[12];

  // ws: ebtab 128K | CX bf16 4MB | Vt bf16 4MB = 8.5 MB.
  // d_out f32: y [0, 8MB) ; attn_w [8MB, 41.5MB).
  //   Q bf16 at y bytes [0,4M), K bf16 at y bytes [4M,8M) -> dead before k_outln writes y.
  char*  ws    = (char*)d_ws;
  float* ebtab = (float*)ws;
  u16*   CX    = (u16*)(ws + 131072);
  u16*   Vt    = (u16*)(ws + 131072 + 4194304);
  float* y     = (float*)d_out;
  float* aw    = y + 2097152;
  u16*   Q     = (u16*)y;
  u16*   K     = (u16*)((char*)y + 4194304);

  const float qscale = 0.25503486f;   // log2(e)/sqrt(32) folded into Q

  k_bias_setup<<<16, 256, 0, stream>>>(dib, drb, ebtab);
  k_proj<<<256, 256, 0, stream>>>(x, wq, bq, Q,  qscale, 0);
  k_proj<<<256, 256, 0, stream>>>(x, wk, bk, K,  1.0f,   0);
  k_proj<<<256, 256, 0, stream>>>(x, wv_, bv, Vt, 1.0f,  1);
  k_attn_fused<<<dim3(64, 8), 256, 0, stream>>>(Q, K, Vt, ebtab, CX, aw);
  k_outln<<<256, 256, 0, stream>>>(CX, wo, bo, x, lng, lnb, y);  // overwrites Q,K (dead)
}